// Round 1
// baseline (151.446 us; speedup 1.0000x reference)
//
#include <hip/hip_runtime.h>

// Problem constants (match reference)
namespace {
constexpr int Bc     = 4;
constexpr int Nc     = 16384;
constexpr int Kc     = 27;        // 3^3
constexpr int SHIFTc = 3;
constexpr int BASEc  = 70;        // CMAX + 2*KS
constexpr int BASE3c = BASEc * BASEc * BASEc;   // 343000
constexpr int TABLEc = Bc * BASE3c;             // 1,372,000 (dense key space)
constexpr int NKc    = Nc * Kc;                 // 442,368
constexpr int Tc     = Bc * NKc;                // 1,769,472
constexpr int SBLOCK = 256;
constexpr int SITEMS = 8;
constexpr int SCHUNK = SBLOCK * SITEMS;         // 2048
constexpr int NBLK   = (Tc + SCHUNK - 1) / SCHUNK;  // 864 (exact: 864*2048 == Tc)
constexpr int INTMAXv = 0x7fffffff;
}

__device__ __forceinline__ void decode_t(int t, int& b, int& idx, int& k) {
    b = t / NKc;
    int rem = t - b * NKc;
    idx = rem / Kc;
    k = rem - idx * Kc;
}

// Returns dense key; also outputs idx, k and neighbor coords (pre-shift)
__device__ __forceinline__ int make_key(const int* __restrict__ coords,
                                        const int* __restrict__ batch,
                                        int t, int& idx_o, int& k_o,
                                        int& nx, int& ny, int& nz) {
    int b, idx, k;
    decode_t(t, b, idx, k);
    int cbase = (b * Nc + idx) * 3;
    int x = coords[cbase + 0];
    int y = coords[cbase + 1];
    int z = coords[cbase + 2];
    int dx = k / 9 - 1;
    int dy = (k / 3) % 3 - 1;
    int dz = k % 3 - 1;
    nx = x + dx; ny = y + dy; nz = z + dz;
    int bb = batch[b * Nc + idx];
    idx_o = idx; k_o = k;
    return bb * BASE3c + ((nx + SHIFTc) * BASEc + (ny + SHIFTc)) * BASEc + (nz + SHIFTc);
}

// K1: init first-occurrence table to INT_MAX
__global__ void k1_init(int* __restrict__ first) {
    int i = blockIdx.x * blockDim.x + threadIdx.x;
    if (i < TABLEc) first[i] = INTMAXv;
}

// K2: first[key] = min over t
__global__ void k2_atomic_min(const int* __restrict__ coords,
                              const int* __restrict__ batch,
                              int* __restrict__ first) {
    int t = blockIdx.x * blockDim.x + threadIdx.x;
    if (t >= Tc) return;
    int idx, k, nx, ny, nz;
    int key = make_key(coords, batch, t, idx, k, nx, ny, nz);
    atomicMin(&first[key], t);
}

// K3: per-block sums of pred(t) = (first[key(t)] == t)
__global__ void k3_block_sums(const int* __restrict__ coords,
                              const int* __restrict__ batch,
                              const int* __restrict__ first,
                              int* __restrict__ blockSums) {
    __shared__ int sdata[SBLOCK];
    int bid = blockIdx.x, tid = threadIdx.x;
    int t0 = bid * SCHUNK + tid * SITEMS;
    int sum = 0;
    #pragma unroll
    for (int i = 0; i < SITEMS; ++i) {
        int t = t0 + i;
        if (t < Tc) {
            int idx, k, nx, ny, nz;
            int key = make_key(coords, batch, t, idx, k, nx, ny, nz);
            sum += (first[key] == t) ? 1 : 0;
        }
    }
    sdata[tid] = sum;
    __syncthreads();
    for (int off = SBLOCK / 2; off > 0; off >>= 1) {
        if (tid < off) sdata[tid] += sdata[tid + off];
        __syncthreads();
    }
    if (tid == 0) blockSums[bid] = sdata[0];
}

// K4: single-block exclusive scan of the NBLK block sums; writes num_out
__global__ void k4_scan_blocks(const int* __restrict__ blockSums,
                               int* __restrict__ blockOff,
                               int* __restrict__ total,
                               int* __restrict__ num_out_dst) {
    __shared__ int sdata[1024];
    int tid = threadIdx.x;
    int v = (tid < NBLK) ? blockSums[tid] : 0;
    sdata[tid] = v;
    __syncthreads();
    for (int off = 1; off < 1024; off <<= 1) {
        int u = (tid >= off) ? sdata[tid - off] : 0;
        __syncthreads();
        sdata[tid] += u;
        __syncthreads();
    }
    if (tid < NBLK) blockOff[tid] = sdata[tid] - v;  // exclusive
    if (tid == 1023) {
        total[0] = sdata[1023];
        num_out_dst[0] = sdata[1023];
    }
}

// K5: block scan + scatter ranks and out_key rows for first occurrences
__global__ void k5_scan_scatter(const int* __restrict__ coords,
                                const int* __restrict__ batch,
                                const int* __restrict__ first,
                                int* __restrict__ rank_table,
                                const int* __restrict__ blockOff,
                                int* __restrict__ out_key) {
    __shared__ int sdata[SBLOCK];
    int bid = blockIdx.x, tid = threadIdx.x;
    int t0 = bid * SCHUNK + tid * SITEMS;
    int pred[SITEMS];
    int keys[SITEMS];
    int nxs[SITEMS], nys[SITEMS], nzs[SITEMS];
    int sum = 0;
    #pragma unroll
    for (int i = 0; i < SITEMS; ++i) {
        int t = t0 + i;
        int p = 0;
        if (t < Tc) {
            int idx, k;
            int key = make_key(coords, batch, t, idx, k, nxs[i], nys[i], nzs[i]);
            keys[i] = key;
            p = (first[key] == t) ? 1 : 0;
        }
        pred[i] = p;
        sum += p;
    }
    sdata[tid] = sum;
    __syncthreads();
    // inclusive Hillis-Steele over 256 thread totals
    for (int off = 1; off < SBLOCK; off <<= 1) {
        int u = (tid >= off) ? sdata[tid - off] : 0;
        __syncthreads();
        sdata[tid] += u;
        __syncthreads();
    }
    int rbase = blockOff[bid] + (sdata[tid] - sum);  // exclusive within grid
    int running = 0;
    #pragma unroll
    for (int i = 0; i < SITEMS; ++i) {
        if (pred[i]) {
            int r = rbase + running;
            rank_table[keys[i]] = r;
            out_key[3 * r + 0] = nxs[i];
            out_key[3 * r + 1] = nys[i];
            out_key[3 * r + 2] = nzs[i];
            running += 1;
        }
    }
}

// K6: final outputs: in_idx, out_idx, rel_pos, and -1 fill of out_key tail
__global__ void k6_outputs(const int* __restrict__ coords,
                           const int* __restrict__ batch,
                           const int* __restrict__ rank_table,
                           int* __restrict__ in_idx,
                           int* __restrict__ out_idx,
                           int* __restrict__ rel_pos,
                           int* __restrict__ out_key,
                           const int* __restrict__ total) {
    int t = blockIdx.x * blockDim.x + threadIdx.x;
    if (t >= Tc) return;
    int idx, k, nx, ny, nz;
    int key = make_key(coords, batch, t, idx, k, nx, ny, nz);
    in_idx[t] = idx;
    rel_pos[t] = k;
    out_idx[t] = rank_table[key];
    int num = total[0];
    if (t >= num) {
        out_key[3 * t + 0] = -1;
        out_key[3 * t + 1] = -1;
        out_key[3 * t + 2] = -1;
    }
}

extern "C" void kernel_launch(void* const* d_in, const int* in_sizes, int n_in,
                              void* d_out, int out_size, void* d_ws, size_t ws_size,
                              hipStream_t stream) {
    const int* coords = (const int*)d_in[0];   // [B, N, 3]
    const int* batch  = (const int*)d_in[1];   // [B, N]
    int* out = (int*)d_out;
    int* in_idx  = out;                 // [T]
    int* out_idx = out + Tc;            // [T]
    int* rel_pos = out + 2 * Tc;        // [T]
    int* out_key = out + 3 * Tc;        // [T,3]
    int* num_out = out + 6 * Tc;        // [1]

    // workspace layout (ints)
    int* ws = (int*)d_ws;
    int* first      = ws;                       // TABLEc
    int* rank_table = ws + TABLEc;              // TABLEc
    int* blockSums  = ws + 2 * TABLEc;          // NBLK
    int* blockOff   = blockSums + NBLK;         // NBLK
    int* total      = blockOff + NBLK;          // 1

    k1_init<<<(TABLEc + 255) / 256, 256, 0, stream>>>(first);
    k2_atomic_min<<<(Tc + 255) / 256, 256, 0, stream>>>(coords, batch, first);
    k3_block_sums<<<NBLK, SBLOCK, 0, stream>>>(coords, batch, first, blockSums);
    k4_scan_blocks<<<1, 1024, 0, stream>>>(blockSums, blockOff, total, num_out);
    k5_scan_scatter<<<NBLK, SBLOCK, 0, stream>>>(coords, batch, first, rank_table,
                                                 blockOff, out_key);
    k6_outputs<<<(Tc + 255) / 256, 256, 0, stream>>>(coords, batch, rank_table,
                                                     in_idx, out_idx, rel_pos,
                                                     out_key, total);
}